// Round 8
// baseline (304.403 us; speedup 1.0000x reference)
//
#include <hip/hip_runtime.h>
#include <hip/hip_bf16.h>
#include <hip/hip_fp8.h>
#include <math.h>

typedef _Float16 f16x4 __attribute__((ext_vector_type(4)));
typedef _Float16 f16x8 __attribute__((ext_vector_type(8)));
typedef float f32x4 __attribute__((ext_vector_type(4)));
typedef __fp16 hf8 __attribute__((ext_vector_type(8)));

#define DIM 128
#define LDST 136   // padded LDS row stride in f16 elems
#define NB 16      // col buckets for the locality sweep (~1.2MB kv each)

#if defined(__has_builtin)
#if __has_builtin(__builtin_amdgcn_cvt_pk_fp8_f32) && __has_builtin(__builtin_amdgcn_cvt_pk_f32_fp8)
#define HAVE_FP8CVT 1
#endif
#endif

__device__ __forceinline__ unsigned int pack_fp8x4(float f0, float f1, float f2, float f3) {
#ifdef HAVE_FP8CVT
    int w = __builtin_amdgcn_cvt_pk_fp8_f32(f0, f1, 0, false);
    w = __builtin_amdgcn_cvt_pk_fp8_f32(f2, f3, w, true);
    return (unsigned int)w;
#else
    __hip_fp8_e4m3 a(f0), b(f1), c(f2), d(f3);
    return (unsigned int)a.__x | ((unsigned int)b.__x << 8) |
           ((unsigned int)c.__x << 16) | ((unsigned int)d.__x << 24);
#endif
}

__device__ __forceinline__ void dot_fp8x4(float& d, unsigned int w, const float* qv) {
#ifdef HAVE_FP8CVT
    auto lo = __builtin_amdgcn_cvt_pk_f32_fp8((int)w, false);
    auto hi = __builtin_amdgcn_cvt_pk_f32_fp8((int)w, true);
    d += lo[0] * qv[0] + lo[1] * qv[1] + hi[0] * qv[2] + hi[1] * qv[3];
#else
    for (int j = 0; j < 4; ++j) {
        __hip_fp8_e4m3 t; t.__x = (unsigned char)((w >> (8 * j)) & 0xff);
        d += (float)t * qv[j];
    }
#endif
}

// ---------------------------------------------------------------------------
// Kernel 1: transpose + f16-convert the three 128x128 weight matrices.
// ---------------------------------------------------------------------------
__global__ __launch_bounds__(256) void prep_w_kernel(
    const float* __restrict__ Wq, const float* __restrict__ Wk,
    const float* __restrict__ Wv, _Float16* __restrict__ Wt)
{
    const float* W = (blockIdx.y == 0) ? Wq : (blockIdx.y == 1) ? Wk : Wv;
    _Float16* dst = Wt + (size_t)blockIdx.y * DIM * DIM;
    int idx = blockIdx.x * 256 + threadIdx.x;
    int k = idx >> 7;
    int n = idx & 127;
    dst[n * DIM + k] = (_Float16)W[idx];
}

// ---------------------------------------------------------------------------
// Kernel 2: CSR row_ptr from sorted rows[] via per-row lower_bound.
// ---------------------------------------------------------------------------
__global__ __launch_bounds__(256) void row_ptr_kernel(
    const int* __restrict__ rows, int* __restrict__ row_ptr, int n, int e)
{
    int r = blockIdx.x * 256 + threadIdx.x;
    if (r > n) return;
    if (r == n) { row_ptr[n] = e; return; }
    int lo = 0, hi = e;
    while (lo < hi) {
        int mid = (lo + hi) >> 1;
        if (rows[mid] < r) lo = mid + 1; else hi = mid;
    }
    row_ptr[r] = lo;
}

// ---------------------------------------------------------------------------
// Kernels 2b-2d: reorder each row's edges by col bucket so all waves sweep
// col-space in approximate lockstep (instantaneous kv working set ~1-3MB,
// L2-resident per XCD). Output: packed[e] = {col, adj_bits}, bucket-ordered
// within each row's CSR segment. Sum-order change is tolerance-absorbed.
// ---------------------------------------------------------------------------
__global__ __launch_bounds__(256) void count_kernel(
    const int* __restrict__ rows, const int* __restrict__ cols,
    int* __restrict__ cnt, int e, int bsize)
{
    int i = blockIdx.x * 256 + threadIdx.x;
    if (i >= e) return;
    int b = cols[i] / bsize;
    atomicAdd(&cnt[rows[i] * NB + b], 1);
}

__global__ __launch_bounds__(256) void prefix_kernel(
    const int* __restrict__ row_ptr, int* __restrict__ cnt, int n)
{
    int r = blockIdx.x * 256 + threadIdx.x;
    if (r >= n) return;
    int acc = row_ptr[r];
    for (int b = 0; b < NB; ++b) {
        int c = cnt[r * NB + b];
        cnt[r * NB + b] = acc;   // becomes "next free slot"
        acc += c;
    }
}

__global__ __launch_bounds__(256) void scatter_kernel(
    const int* __restrict__ rows, const int* __restrict__ cols,
    const float* __restrict__ adj, int* __restrict__ cnt,
    uint2* __restrict__ packed, int e, int bsize)
{
    int i = blockIdx.x * 256 + threadIdx.x;
    if (i >= e) return;
    int c = cols[i];
    int b = c / bsize;
    int slot = atomicAdd(&cnt[rows[i] * NB + b], 1);
    uint2 p;
    p.x = (unsigned int)c;
    p.y = __float_as_uint(adj[i]);
    packed[slot] = p;
}

// ---------------------------------------------------------------------------
// Kernel 3: fused projection GEMM  Y = gelu(X @ W + b).
// which==0 -> qf (f16), which==1 -> k8 (fp8 e4m3), which==2 -> v16 (f16).
// ---------------------------------------------------------------------------
__global__ __launch_bounds__(256, 2) void proj_gemm_kernel(
    const float* __restrict__ query, const float* __restrict__ memory,
    const _Float16* __restrict__ Wt,
    const float* __restrict__ bq, const float* __restrict__ bk,
    const float* __restrict__ bv,
    _Float16* __restrict__ qf, unsigned char* __restrict__ k8,
    _Float16* __restrict__ v16, int n, int m)
{
    __shared__ _Float16 xs[128 * LDST];

    int which = blockIdx.y;
    const float* X    = (which == 0) ? query : memory;
    const _Float16* Wm = Wt + (size_t)which * DIM * DIM;
    const float* bias = (which == 0) ? bq : (which == 1) ? bk : bv;
    int R             = (which == 0) ? n : m;

    int tid = threadIdx.x;
    int rowblock = blockIdx.x * 128;
    if (rowblock >= R) return;

    for (int it = 0; it < 16; ++it) {
        int flat = it * 256 + tid;
        int r  = flat >> 5;
        int c4 = (flat & 31) * 4;
        int gr = rowblock + r;
        if (gr >= R) gr = R - 1;
        float4 x = *(const float4*)(X + (size_t)gr * DIM + c4);
        f16x4 w4;
        w4[0] = (_Float16)x.x; w4[1] = (_Float16)x.y;
        w4[2] = (_Float16)x.z; w4[3] = (_Float16)x.w;
        *(f16x4*)(&xs[r * LDST + c4]) = w4;
    }
    __syncthreads();

    int wave = tid >> 6;
    int lane = tid & 63;
    int quad = lane >> 4;
    int l16  = lane & 15;
    int wrow = wave * 32;

    f16x8 afrag[2][4];
    for (int rt = 0; rt < 2; ++rt)
        for (int ks = 0; ks < 4; ++ks)
            afrag[rt][ks] = *(const f16x8*)(&xs[(wrow + rt * 16 + l16) * LDST + quad * 8 + ks * 32]);

    f32x4 acc[8][2];
    for (int ct = 0; ct < 8; ++ct) { acc[ct][0] = {0,0,0,0}; acc[ct][1] = {0,0,0,0}; }
    for (int ct = 0; ct < 8; ++ct) {
        const _Float16* wp = Wm + (size_t)(ct * 16 + l16) * DIM + quad * 8;
        for (int ks = 0; ks < 4; ++ks) {
            f16x8 b = *(const f16x8*)(wp + ks * 32);
            acc[ct][0] = __builtin_amdgcn_mfma_f32_16x16x32_f16(afrag[0][ks], b, acc[ct][0], 0, 0, 0);
            acc[ct][1] = __builtin_amdgcn_mfma_f32_16x16x32_f16(afrag[1][ks], b, acc[ct][1], 0, 0, 0);
        }
    }

    __syncthreads();
    for (int ct = 0; ct < 8; ++ct) {
        float bval = bias[ct * 16 + l16];
        for (int rt = 0; rt < 2; ++rt) {
            for (int reg = 0; reg < 4; ++reg) {
                float x = acc[ct][rt][reg] + bval;
                float t  = 0.7978845608028654f * (x + 0.044715f * x * x * x);
                float th = 1.0f - 2.0f / (__expf(2.0f * t) + 1.0f);
                float g  = 0.5f * x * (1.0f + th);
                xs[(wrow + rt * 16 + quad * 4 + reg) * LDST + ct * 16 + l16] = (_Float16)g;
            }
        }
    }
    __syncthreads();

    if (which == 1) {
        for (int it = 0; it < 8; ++it) {
            int flat = it * 256 + tid;
            int r  = flat >> 4;
            int c8 = (flat & 15) * 8;
            int gr = rowblock + r;
            if (gr < R) {
                f16x8 h = *(const f16x8*)(&xs[r * LDST + c8]);
                unsigned int w0 = pack_fp8x4((float)h[0], (float)h[1], (float)h[2], (float)h[3]);
                unsigned int w1 = pack_fp8x4((float)h[4], (float)h[5], (float)h[6], (float)h[7]);
                *(uint2*)(k8 + (size_t)gr * DIM + c8) = make_uint2(w0, w1);
            }
        }
    } else {
        _Float16* Ybase = (which == 0) ? qf : v16;
        for (int it = 0; it < 8; ++it) {
            int flat = it * 256 + tid;
            int r  = flat >> 4;
            int c8 = (flat & 15) * 8;
            int gr = rowblock + r;
            if (gr < R) {
                f16x8 vv = *(const f16x8*)(&xs[r * LDST + c8]);
                *(f16x8*)(Ybase + (size_t)gr * DIM + c8) = vv;
            }
        }
    }
}

// ---------------------------------------------------------------------------
// Kernel 4: per-row edge attention (R6 skeleton: one wave per row, 16
// lanes/edge, 8 edges in flight, plain-exp softmax, fp8 k / f16 v).
// Changes vs R6: (col,adj) read as one packed uint2; q pre-scaled; edges
// arrive bucket-ordered (locality sweep handled by the prep reorder).
// ---------------------------------------------------------------------------
__global__ __launch_bounds__(256) void edge_attn_kernel(
    const __fp16* __restrict__ qf, const unsigned char* __restrict__ k8,
    const __fp16* __restrict__ v16, const uint2* __restrict__ packed,
    const int* __restrict__ row_ptr, float* __restrict__ out, int n)
{
    int row = blockIdx.x * 4 + (threadIdx.x >> 6);
    if (row >= n) return;
    int lane    = threadIdx.x & 63;
    int quarter = lane >> 4;
    int l16     = lane & 15;

    int start = row_ptr[row];
    int end   = row_ptr[row + 1];

    const float scale = 0.08838834764831845f;   // 1/sqrt(128)
    float qv[8];
    {
        hf8 q8 = *(const hf8*)(qf + (size_t)row * DIM + l16 * 8);
#pragma unroll
        for (int j = 0; j < 8; ++j) qv[j] = (float)q8[j] * scale;
    }

    float s_sum = 0.0f;
    float acc[8];
#pragma unroll
    for (int j = 0; j < 8; ++j) acc[j] = 0.0f;

    for (int g = start; g < end; g += 8) {
        int eA = g + quarter;
        int eB = g + 4 + quarter;
        bool vA = eA < end;
        bool vB = eB < end;
        int last = end - 1;
        int iA = vA ? eA : last;
        int iB = vB ? eB : last;
        uint2 pkA = packed[iA];
        uint2 pkB = packed[iB];
        int   cA = (int)pkA.x;
        int   cB = (int)pkB.x;
        float aA = __uint_as_float(pkA.y);
        float aB = __uint_as_float(pkB.y);

        uint2 rA = *(const uint2*)(k8 + (size_t)cA * DIM + l16 * 8);
        uint2 rB = *(const uint2*)(k8 + (size_t)cB * DIM + l16 * 8);
        hf8 vA8 = *(const hf8*)(v16 + (size_t)cA * DIM + l16 * 8);
        hf8 vB8 = *(const hf8*)(v16 + (size_t)cB * DIM + l16 * 8);

        float dA = 0.0f, dB = 0.0f;
        dot_fp8x4(dA, rA.x, qv);
        dot_fp8x4(dA, rA.y, qv + 4);
        dot_fp8x4(dB, rB.x, qv);
        dot_fp8x4(dB, rB.y, qv + 4);
        dA += __shfl_xor(dA, 1); dB += __shfl_xor(dB, 1);
        dA += __shfl_xor(dA, 2); dB += __shfl_xor(dB, 2);
        dA += __shfl_xor(dA, 4); dB += __shfl_xor(dB, 4);
        dA += __shfl_xor(dA, 8); dB += __shfl_xor(dB, 8);

        float pA_ = vA ? __expf(dA * aA) : 0.0f;
        float pB_ = vB ? __expf(dB * aB) : 0.0f;
        s_sum += pA_ + pB_;
#pragma unroll
        for (int j = 0; j < 8; ++j)
            acc[j] += pA_ * (float)vA8[j] + pB_ * (float)vB8[j];
    }

    s_sum += __shfl_xor(s_sum, 16);
    s_sum += __shfl_xor(s_sum, 32);
#pragma unroll
    for (int j = 0; j < 8; ++j) {
        acc[j] += __shfl_xor(acc[j], 16);
        acc[j] += __shfl_xor(acc[j], 32);
    }
    float inv = (s_sum > 0.0f) ? 1.0f / s_sum : 0.0f;

    if (quarter == 0) {
        float4* dst = (float4*)(out + (size_t)row * DIM + l16 * 8);
        dst[0] = make_float4(acc[0] * inv, acc[1] * inv, acc[2] * inv, acc[3] * inv);
        dst[1] = make_float4(acc[4] * inv, acc[5] * inv, acc[6] * inv, acc[7] * inv);
    }
}

// ---------------------------------------------------------------------------
extern "C" void kernel_launch(void* const* d_in, const int* in_sizes, int n_in,
                              void* d_out, int out_size, void* d_ws, size_t ws_size,
                              hipStream_t stream)
{
    const float* query    = (const float*)d_in[0];
    const float* memory   = (const float*)d_in[1];
    const float* adj_vals = (const float*)d_in[2];
    const float* Wq       = (const float*)d_in[3];
    const float* bq       = (const float*)d_in[4];
    const float* Wk       = (const float*)d_in[5];
    const float* bk       = (const float*)d_in[6];
    const float* Wv       = (const float*)d_in[7];
    const float* bv       = (const float*)d_in[8];
    const int*   rows     = (const int*)d_in[9];
    const int*   cols     = (const int*)d_in[10];
    float* out = (float*)d_out;

    int n = in_sizes[0] / DIM;   // 50000
    int m = in_sizes[1] / DIM;   // 50000
    int e = in_sizes[9];         // 1600000
    int bsize = (m + NB - 1) / NB;

    // workspace layout (16B-aligned)
    char* ws = (char*)d_ws;
    size_t off = 0;
    _Float16* Wt = (_Float16*)(ws + off); off += (size_t)3 * DIM * DIM * 2;    // 96KB
    _Float16* qf = (_Float16*)(ws + off); off += (size_t)n * DIM * 2;          // 12.8MB
    _Float16* v16 = (_Float16*)(ws + off); off += (size_t)m * DIM * 2;         // 12.8MB
    unsigned char* k8 = (unsigned char*)(ws + off); off += (size_t)m * DIM;    // 6.4MB
    uint2* packed = (uint2*)(ws + off);   off += (size_t)e * 8;                // 12.8MB
    int* row_ptr = (int*)(ws + off);      off += (size_t)(n + 1) * 4;          // 200KB
    off = (off + 15) & ~(size_t)15;
    int* cnt = (int*)(ws + off);          off += (size_t)n * NB * 4;           // 3.2MB

    prep_w_kernel<<<dim3(64, 3), 256, 0, stream>>>(Wq, Wk, Wv, Wt);

    row_ptr_kernel<<<dim3((n + 1 + 255) / 256), 256, 0, stream>>>(rows, row_ptr, n, e);

    hipMemsetAsync(cnt, 0, (size_t)n * NB * 4, stream);
    count_kernel<<<dim3((e + 255) / 256), 256, 0, stream>>>(rows, cols, cnt, e, bsize);
    prefix_kernel<<<dim3((n + 255) / 256), 256, 0, stream>>>(row_ptr, cnt, n);
    scatter_kernel<<<dim3((e + 255) / 256), 256, 0, stream>>>(rows, cols, adj_vals, cnt, packed, e, bsize);

    proj_gemm_kernel<<<dim3((n + 127) / 128, 3), 256, 0, stream>>>(
        query, memory, Wt, bq, bk, bv, qf, k8, v16, n, m);

    edge_attn_kernel<<<dim3((n + 3) / 4), 256, 0, stream>>>(
        (const __fp16*)qf, k8, (const __fp16*)v16, packed, row_ptr, out, n);
}

// Round 10
// 238.727 us; speedup vs baseline: 1.2751x; 1.2751x over previous
//
#include <hip/hip_runtime.h>
#include <hip/hip_bf16.h>
#include <hip/hip_fp8.h>
#include <math.h>

typedef _Float16 f16x4 __attribute__((ext_vector_type(4)));
typedef _Float16 f16x8 __attribute__((ext_vector_type(8)));
typedef float f32x4 __attribute__((ext_vector_type(4)));
typedef __fp16 hf8 __attribute__((ext_vector_type(8)));

#define DIM 128
#define LDST 136     // padded LDS row stride in f16 elems
#define KVREC 384    // interleaved record: [0,128) k fp8, [128,384) v f16

#if defined(__has_builtin)
#if __has_builtin(__builtin_amdgcn_cvt_pk_fp8_f32) && __has_builtin(__builtin_amdgcn_cvt_pk_f32_fp8)
#define HAVE_FP8CVT 1
#endif
#endif

__device__ __forceinline__ unsigned int pack_fp8x4(float f0, float f1, float f2, float f3) {
#ifdef HAVE_FP8CVT
    int w = __builtin_amdgcn_cvt_pk_fp8_f32(f0, f1, 0, false);
    w = __builtin_amdgcn_cvt_pk_fp8_f32(f2, f3, w, true);
    return (unsigned int)w;
#else
    __hip_fp8_e4m3 a(f0), b(f1), c(f2), d(f3);
    return (unsigned int)a.__x | ((unsigned int)b.__x << 8) |
           ((unsigned int)c.__x << 16) | ((unsigned int)d.__x << 24);
#endif
}

__device__ __forceinline__ void dot_fp8x4(float& d, unsigned int w, const float* qv) {
#ifdef HAVE_FP8CVT
    auto lo = __builtin_amdgcn_cvt_pk_f32_fp8((int)w, false);
    auto hi = __builtin_amdgcn_cvt_pk_f32_fp8((int)w, true);
    d += lo[0] * qv[0] + lo[1] * qv[1] + hi[0] * qv[2] + hi[1] * qv[3];
#else
    for (int j = 0; j < 4; ++j) {
        __hip_fp8_e4m3 t; t.__x = (unsigned char)((w >> (8 * j)) & 0xff);
        d += (float)t * qv[j];
    }
#endif
}

// ---------------------------------------------------------------------------
// Kernel 1: transpose + f16-convert the three 128x128 weight matrices.
// ---------------------------------------------------------------------------
__global__ __launch_bounds__(256) void prep_w_kernel(
    const float* __restrict__ Wq, const float* __restrict__ Wk,
    const float* __restrict__ Wv, _Float16* __restrict__ Wt)
{
    const float* W = (blockIdx.y == 0) ? Wq : (blockIdx.y == 1) ? Wk : Wv;
    _Float16* dst = Wt + (size_t)blockIdx.y * DIM * DIM;
    int idx = blockIdx.x * 256 + threadIdx.x;
    int k = idx >> 7;
    int n = idx & 127;
    dst[n * DIM + k] = (_Float16)W[idx];
}

// ---------------------------------------------------------------------------
// Kernel 2: CSR row_ptr from sorted rows[] via per-row lower_bound.
// ---------------------------------------------------------------------------
__global__ __launch_bounds__(256) void row_ptr_kernel(
    const int* __restrict__ rows, int* __restrict__ row_ptr, int n, int e)
{
    int r = blockIdx.x * 256 + threadIdx.x;
    if (r > n) return;
    if (r == n) { row_ptr[n] = e; return; }
    int lo = 0, hi = e;
    while (lo < hi) {
        int mid = (lo + hi) >> 1;
        if (rows[mid] < r) lo = mid + 1; else hi = mid;
    }
    row_ptr[r] = lo;
}

// ---------------------------------------------------------------------------
// Kernel 3: fused projection GEMM  Y = gelu(X @ W + b).
// which==0 -> qf (f16); which==1 -> k fp8 into kvrec[col*384 + 0..128);
// which==2 -> v f16 into kvrec[col*384 + 128..384).
// ---------------------------------------------------------------------------
__global__ __launch_bounds__(256, 2) void proj_gemm_kernel(
    const float* __restrict__ query, const float* __restrict__ memory,
    const _Float16* __restrict__ Wt,
    const float* __restrict__ bq, const float* __restrict__ bk,
    const float* __restrict__ bv,
    _Float16* __restrict__ qf, unsigned char* __restrict__ kvrec,
    int n, int m)
{
    __shared__ _Float16 xs[128 * LDST];

    int which = blockIdx.y;
    const float* X    = (which == 0) ? query : memory;
    const _Float16* Wm = Wt + (size_t)which * DIM * DIM;
    const float* bias = (which == 0) ? bq : (which == 1) ? bk : bv;
    int R             = (which == 0) ? n : m;

    int tid = threadIdx.x;
    int rowblock = blockIdx.x * 128;
    if (rowblock >= R) return;

    for (int it = 0; it < 16; ++it) {
        int flat = it * 256 + tid;
        int r  = flat >> 5;
        int c4 = (flat & 31) * 4;
        int gr = rowblock + r;
        if (gr >= R) gr = R - 1;
        float4 x = *(const float4*)(X + (size_t)gr * DIM + c4);
        f16x4 w4;
        w4[0] = (_Float16)x.x; w4[1] = (_Float16)x.y;
        w4[2] = (_Float16)x.z; w4[3] = (_Float16)x.w;
        *(f16x4*)(&xs[r * LDST + c4]) = w4;
    }
    __syncthreads();

    int wave = tid >> 6;
    int lane = tid & 63;
    int quad = lane >> 4;
    int l16  = lane & 15;
    int wrow = wave * 32;

    f16x8 afrag[2][4];
    for (int rt = 0; rt < 2; ++rt)
        for (int ks = 0; ks < 4; ++ks)
            afrag[rt][ks] = *(const f16x8*)(&xs[(wrow + rt * 16 + l16) * LDST + quad * 8 + ks * 32]);

    f32x4 acc[8][2];
    for (int ct = 0; ct < 8; ++ct) { acc[ct][0] = {0,0,0,0}; acc[ct][1] = {0,0,0,0}; }
    for (int ct = 0; ct < 8; ++ct) {
        const _Float16* wp = Wm + (size_t)(ct * 16 + l16) * DIM + quad * 8;
        for (int ks = 0; ks < 4; ++ks) {
            f16x8 b = *(const f16x8*)(wp + ks * 32);
            acc[ct][0] = __builtin_amdgcn_mfma_f32_16x16x32_f16(afrag[0][ks], b, acc[ct][0], 0, 0, 0);
            acc[ct][1] = __builtin_amdgcn_mfma_f32_16x16x32_f16(afrag[1][ks], b, acc[ct][1], 0, 0, 0);
        }
    }

    __syncthreads();
    for (int ct = 0; ct < 8; ++ct) {
        float bval = bias[ct * 16 + l16];
        for (int rt = 0; rt < 2; ++rt) {
            for (int reg = 0; reg < 4; ++reg) {
                float x = acc[ct][rt][reg] + bval;
                float t  = 0.7978845608028654f * (x + 0.044715f * x * x * x);
                float th = 1.0f - 2.0f / (__expf(2.0f * t) + 1.0f);
                float g  = 0.5f * x * (1.0f + th);
                xs[(wrow + rt * 16 + quad * 4 + reg) * LDST + ct * 16 + l16] = (_Float16)g;
            }
        }
    }
    __syncthreads();

    if (which == 1) {
        // k fp8: 8 f16 -> 8 bytes at kvrec[gr*384 + c8]
        for (int it = 0; it < 8; ++it) {
            int flat = it * 256 + tid;
            int r  = flat >> 4;
            int c8 = (flat & 15) * 8;
            int gr = rowblock + r;
            if (gr < R) {
                f16x8 h = *(const f16x8*)(&xs[r * LDST + c8]);
                unsigned int w0 = pack_fp8x4((float)h[0], (float)h[1], (float)h[2], (float)h[3]);
                unsigned int w1 = pack_fp8x4((float)h[4], (float)h[5], (float)h[6], (float)h[7]);
                *(uint2*)(kvrec + (size_t)gr * KVREC + c8) = make_uint2(w0, w1);
            }
        }
    } else if (which == 2) {
        // v f16: 16B at kvrec[gr*384 + 128 + c8*2]
        for (int it = 0; it < 8; ++it) {
            int flat = it * 256 + tid;
            int r  = flat >> 4;
            int c8 = (flat & 15) * 8;
            int gr = rowblock + r;
            if (gr < R) {
                f16x8 vv = *(const f16x8*)(&xs[r * LDST + c8]);
                *(f16x8*)(kvrec + (size_t)gr * KVREC + 128 + c8 * 2) = vv;
            }
        }
    } else {
        for (int it = 0; it < 8; ++it) {
            int flat = it * 256 + tid;
            int r  = flat >> 4;
            int c8 = (flat & 15) * 8;
            int gr = rowblock + r;
            if (gr < R) {
                f16x8 vv = *(const f16x8*)(&xs[r * LDST + c8]);
                *(f16x8*)(qf + (size_t)gr * DIM + c8) = vv;
            }
        }
    }
}

// ---------------------------------------------------------------------------
// Kernel 4: per-row edge attention (R6 skeleton: one wave per row, 16
// lanes/edge, 8 edges in flight, plain-exp softmax, fp8 k / f16 v).
// R9: k|v interleaved in one 384B record (DRAM/L3 neighbors on co-miss);
// non-temporal hints on single-use streams (q, cols, adj loads; out store)
// to keep the hot kv set in the per-XCD L2.
// ---------------------------------------------------------------------------
__global__ __launch_bounds__(256) void edge_attn_kernel(
    const __fp16* __restrict__ qf, const unsigned char* __restrict__ kvrec,
    const float* __restrict__ adj_vals, const int* __restrict__ cols,
    const int* __restrict__ row_ptr, float* __restrict__ out, int n)
{
    int row = blockIdx.x * 4 + (threadIdx.x >> 6);
    if (row >= n) return;
    int lane    = threadIdx.x & 63;
    int quarter = lane >> 4;
    int l16     = lane & 15;

    int start = row_ptr[row];
    int end   = row_ptr[row + 1];

    const float scale = 0.08838834764831845f;   // 1/sqrt(128)
    float qv[8];
    {
        hf8 q8 = __builtin_nontemporal_load((const hf8*)(qf + (size_t)row * DIM + l16 * 8));
#pragma unroll
        for (int j = 0; j < 8; ++j) qv[j] = (float)q8[j] * scale;
    }

    float s_sum = 0.0f;
    float acc[8];
#pragma unroll
    for (int j = 0; j < 8; ++j) acc[j] = 0.0f;

    for (int g = start; g < end; g += 8) {
        int eA = g + quarter;
        int eB = g + 4 + quarter;
        bool vA = eA < end;
        bool vB = eB < end;
        int last = end - 1;
        int iA = vA ? eA : last;
        int iB = vB ? eB : last;
        int   cA = __builtin_nontemporal_load(cols + iA);
        int   cB = __builtin_nontemporal_load(cols + iB);
        float aA = __builtin_nontemporal_load(adj_vals + iA);
        float aB = __builtin_nontemporal_load(adj_vals + iB);

        const unsigned char* rAp = kvrec + (size_t)cA * KVREC;
        const unsigned char* rBp = kvrec + (size_t)cB * KVREC;
        uint2 rA = *(const uint2*)(rAp + l16 * 8);
        uint2 rB = *(const uint2*)(rBp + l16 * 8);
        hf8 vA8 = *(const hf8*)(rAp + 128 + l16 * 16);
        hf8 vB8 = *(const hf8*)(rBp + 128 + l16 * 16);

        float dA = 0.0f, dB = 0.0f;
        dot_fp8x4(dA, rA.x, qv);
        dot_fp8x4(dA, rA.y, qv + 4);
        dot_fp8x4(dB, rB.x, qv);
        dot_fp8x4(dB, rB.y, qv + 4);
        dA += __shfl_xor(dA, 1); dB += __shfl_xor(dB, 1);
        dA += __shfl_xor(dA, 2); dB += __shfl_xor(dB, 2);
        dA += __shfl_xor(dA, 4); dB += __shfl_xor(dB, 4);
        dA += __shfl_xor(dA, 8); dB += __shfl_xor(dB, 8);

        float pA_ = vA ? __expf(dA * aA) : 0.0f;
        float pB_ = vB ? __expf(dB * aB) : 0.0f;
        s_sum += pA_ + pB_;
#pragma unroll
        for (int j = 0; j < 8; ++j)
            acc[j] += pA_ * (float)vA8[j] + pB_ * (float)vB8[j];
    }

    s_sum += __shfl_xor(s_sum, 16);
    s_sum += __shfl_xor(s_sum, 32);
#pragma unroll
    for (int j = 0; j < 8; ++j) {
        acc[j] += __shfl_xor(acc[j], 16);
        acc[j] += __shfl_xor(acc[j], 32);
    }
    float inv = (s_sum > 0.0f) ? 1.0f / s_sum : 0.0f;   // empty row -> zeros

    if (quarter == 0) {
        float* dst = out + (size_t)row * DIM + l16 * 8;
        f32x4 o0 = {acc[0] * inv, acc[1] * inv, acc[2] * inv, acc[3] * inv};
        f32x4 o1 = {acc[4] * inv, acc[5] * inv, acc[6] * inv, acc[7] * inv};
        __builtin_nontemporal_store(o0, (f32x4*)dst);
        __builtin_nontemporal_store(o1, (f32x4*)(dst + 4));
    }
}

// ---------------------------------------------------------------------------
extern "C" void kernel_launch(void* const* d_in, const int* in_sizes, int n_in,
                              void* d_out, int out_size, void* d_ws, size_t ws_size,
                              hipStream_t stream)
{
    const float* query    = (const float*)d_in[0];
    const float* memory   = (const float*)d_in[1];
    const float* adj_vals = (const float*)d_in[2];
    const float* Wq       = (const float*)d_in[3];
    const float* bq       = (const float*)d_in[4];
    const float* Wk       = (const float*)d_in[5];
    const float* bk       = (const float*)d_in[6];
    const float* Wv       = (const float*)d_in[7];
    const float* bv       = (const float*)d_in[8];
    const int*   rows     = (const int*)d_in[9];
    const int*   cols     = (const int*)d_in[10];
    float* out = (float*)d_out;

    int n = in_sizes[0] / DIM;   // 50000
    int m = in_sizes[1] / DIM;   // 50000
    int e = in_sizes[9];         // 1600000

    // workspace layout (16B-aligned)
    char* ws = (char*)d_ws;
    size_t off = 0;
    _Float16* Wt = (_Float16*)(ws + off); off += (size_t)3 * DIM * DIM * 2;      // 96KB
    _Float16* qf = (_Float16*)(ws + off); off += (size_t)n * DIM * 2;            // 12.8MB
    unsigned char* kvrec = (unsigned char*)(ws + off); off += (size_t)m * KVREC; // 19.2MB
    int* row_ptr = (int*)(ws + off);      off += (size_t)(n + 1) * 4;            // 200KB

    prep_w_kernel<<<dim3(64, 3), 256, 0, stream>>>(Wq, Wk, Wv, Wt);

    row_ptr_kernel<<<dim3((n + 1 + 255) / 256), 256, 0, stream>>>(rows, row_ptr, n, e);

    proj_gemm_kernel<<<dim3((n + 127) / 128, 3), 256, 0, stream>>>(
        query, memory, Wt, bq, bk, bv, qf, kvrec, n, m);

    edge_attn_kernel<<<dim3((n + 3) / 4), 256, 0, stream>>>(
        (const __fp16*)qf, kvrec, adj_vals, cols, row_ptr, out, n);
}

// Round 11
// 237.493 us; speedup vs baseline: 1.2817x; 1.0052x over previous
//
#include <hip/hip_runtime.h>
#include <hip/hip_bf16.h>
#include <hip/hip_fp8.h>
#include <math.h>

typedef _Float16 f16x4 __attribute__((ext_vector_type(4)));
typedef _Float16 f16x8 __attribute__((ext_vector_type(8)));
typedef float f32x4 __attribute__((ext_vector_type(4)));
typedef __fp16 hf8 __attribute__((ext_vector_type(8)));

#define DIM 128
#define LDST 136   // padded LDS row stride in f16 elems (272B, 16B-aligned)

#if defined(__has_builtin)
#if __has_builtin(__builtin_amdgcn_cvt_pk_fp8_f32) && __has_builtin(__builtin_amdgcn_cvt_pk_f32_fp8)
#define HAVE_FP8CVT 1
#endif
#endif

// pack 4 floats -> 4 fp8 e4m3 bytes in a uint
__device__ __forceinline__ unsigned int pack_fp8x4(float f0, float f1, float f2, float f3) {
#ifdef HAVE_FP8CVT
    int w = __builtin_amdgcn_cvt_pk_fp8_f32(f0, f1, 0, false);
    w = __builtin_amdgcn_cvt_pk_fp8_f32(f2, f3, w, true);
    return (unsigned int)w;
#else
    __hip_fp8_e4m3 a(f0), b(f1), c(f2), d(f3);
    return (unsigned int)a.__x | ((unsigned int)b.__x << 8) |
           ((unsigned int)c.__x << 16) | ((unsigned int)d.__x << 24);
#endif
}

// unpack 4 fp8 e4m3 bytes, accumulate dot with 4 floats of q
__device__ __forceinline__ void dot_fp8x4(float& d, unsigned int w, const float* qv) {
#ifdef HAVE_FP8CVT
    auto lo = __builtin_amdgcn_cvt_pk_f32_fp8((int)w, false);
    auto hi = __builtin_amdgcn_cvt_pk_f32_fp8((int)w, true);
    d += lo[0] * qv[0] + lo[1] * qv[1] + hi[0] * qv[2] + hi[1] * qv[3];
#else
    for (int j = 0; j < 4; ++j) {
        __hip_fp8_e4m3 t; t.__x = (unsigned char)((w >> (8 * j)) & 0xff);
        d += (float)t * qv[j];
    }
#endif
}

// ---------------------------------------------------------------------------
// Kernel 1: transpose + f16-convert the three 128x128 weight matrices.
// ---------------------------------------------------------------------------
__global__ __launch_bounds__(256) void prep_w_kernel(
    const float* __restrict__ Wq, const float* __restrict__ Wk,
    const float* __restrict__ Wv, _Float16* __restrict__ Wt)
{
    const float* W = (blockIdx.y == 0) ? Wq : (blockIdx.y == 1) ? Wk : Wv;
    _Float16* dst = Wt + (size_t)blockIdx.y * DIM * DIM;
    int idx = blockIdx.x * 256 + threadIdx.x;
    int k = idx >> 7;
    int n = idx & 127;
    dst[n * DIM + k] = (_Float16)W[idx];
}

// ---------------------------------------------------------------------------
// Kernel 2: CSR row_ptr from sorted rows[] via per-row lower_bound.
// ---------------------------------------------------------------------------
__global__ __launch_bounds__(256) void row_ptr_kernel(
    const int* __restrict__ rows, int* __restrict__ row_ptr, int n, int e)
{
    int r = blockIdx.x * 256 + threadIdx.x;
    if (r > n) return;
    if (r == n) { row_ptr[n] = e; return; }
    int lo = 0, hi = e;
    while (lo < hi) {
        int mid = (lo + hi) >> 1;
        if (rows[mid] < r) lo = mid + 1; else hi = mid;
    }
    row_ptr[r] = lo;
}

// ---------------------------------------------------------------------------
// Kernel 3: fused projection GEMM  Y = gelu(X @ W + b).
// which==0 -> qf (f16), which==1 -> k8 (fp8 e4m3), which==2 -> v16 (f16).
// ---------------------------------------------------------------------------
__global__ __launch_bounds__(256, 2) void proj_gemm_kernel(
    const float* __restrict__ query, const float* __restrict__ memory,
    const _Float16* __restrict__ Wt,
    const float* __restrict__ bq, const float* __restrict__ bk,
    const float* __restrict__ bv,
    _Float16* __restrict__ qf, unsigned char* __restrict__ k8,
    _Float16* __restrict__ v16, int n, int m)
{
    __shared__ _Float16 xs[128 * LDST];   // 34816 B

    int which = blockIdx.y;
    const float* X    = (which == 0) ? query : memory;
    const _Float16* Wm = Wt + (size_t)which * DIM * DIM;
    const float* bias = (which == 0) ? bq : (which == 1) ? bk : bv;
    int R             = (which == 0) ? n : m;

    int tid = threadIdx.x;
    int rowblock = blockIdx.x * 128;
    if (rowblock >= R) return;

    for (int it = 0; it < 16; ++it) {
        int flat = it * 256 + tid;
        int r  = flat >> 5;
        int c4 = (flat & 31) * 4;
        int gr = rowblock + r;
        if (gr >= R) gr = R - 1;
        float4 x = *(const float4*)(X + (size_t)gr * DIM + c4);
        f16x4 w4;
        w4[0] = (_Float16)x.x; w4[1] = (_Float16)x.y;
        w4[2] = (_Float16)x.z; w4[3] = (_Float16)x.w;
        *(f16x4*)(&xs[r * LDST + c4]) = w4;
    }
    __syncthreads();

    int wave = tid >> 6;
    int lane = tid & 63;
    int quad = lane >> 4;
    int l16  = lane & 15;
    int wrow = wave * 32;

    f16x8 afrag[2][4];
    for (int rt = 0; rt < 2; ++rt)
        for (int ks = 0; ks < 4; ++ks)
            afrag[rt][ks] = *(const f16x8*)(&xs[(wrow + rt * 16 + l16) * LDST + quad * 8 + ks * 32]);

    f32x4 acc[8][2];
    for (int ct = 0; ct < 8; ++ct) { acc[ct][0] = {0,0,0,0}; acc[ct][1] = {0,0,0,0}; }
    for (int ct = 0; ct < 8; ++ct) {
        const _Float16* wp = Wm + (size_t)(ct * 16 + l16) * DIM + quad * 8;
        for (int ks = 0; ks < 4; ++ks) {
            f16x8 b = *(const f16x8*)(wp + ks * 32);
            acc[ct][0] = __builtin_amdgcn_mfma_f32_16x16x32_f16(afrag[0][ks], b, acc[ct][0], 0, 0, 0);
            acc[ct][1] = __builtin_amdgcn_mfma_f32_16x16x32_f16(afrag[1][ks], b, acc[ct][1], 0, 0, 0);
        }
    }

    __syncthreads();
    for (int ct = 0; ct < 8; ++ct) {
        float bval = bias[ct * 16 + l16];
        for (int rt = 0; rt < 2; ++rt) {
            for (int reg = 0; reg < 4; ++reg) {
                float x = acc[ct][rt][reg] + bval;
                float t  = 0.7978845608028654f * (x + 0.044715f * x * x * x);
                float th = 1.0f - 2.0f / (__expf(2.0f * t) + 1.0f);
                float g  = 0.5f * x * (1.0f + th);
                xs[(wrow + rt * 16 + quad * 4 + reg) * LDST + ct * 16 + l16] = (_Float16)g;
            }
        }
    }
    __syncthreads();

    if (which == 1) {
        for (int it = 0; it < 8; ++it) {
            int flat = it * 256 + tid;
            int r  = flat >> 4;
            int c8 = (flat & 15) * 8;
            int gr = rowblock + r;
            if (gr < R) {
                f16x8 h = *(const f16x8*)(&xs[r * LDST + c8]);
                unsigned int w0 = pack_fp8x4((float)h[0], (float)h[1], (float)h[2], (float)h[3]);
                unsigned int w1 = pack_fp8x4((float)h[4], (float)h[5], (float)h[6], (float)h[7]);
                *(uint2*)(k8 + (size_t)gr * DIM + c8) = make_uint2(w0, w1);
            }
        }
    } else {
        _Float16* Ybase = (which == 0) ? qf : v16;
        for (int it = 0; it < 8; ++it) {
            int flat = it * 256 + tid;
            int r  = flat >> 4;
            int c8 = (flat & 15) * 8;
            int gr = rowblock + r;
            if (gr < R) {
                f16x8 vv = *(const f16x8*)(&xs[r * LDST + c8]);
                *(f16x8*)(Ybase + (size_t)gr * DIM + c8) = vv;
            }
        }
    }
}

// ---------------------------------------------------------------------------
// Kernel 4: per-row edge attention (R6 best config: one wave per row, 16
// lanes/edge, 8 edges in flight, plain-exp softmax, fp8 k / f16 v, split
// arrays, no NT hints). R10 post-mortem: interleaved 384B records and
// non-temporal hints both regressed (FETCH +6%, dur +6%) — keep R6 exact.
// ---------------------------------------------------------------------------
__global__ __launch_bounds__(256) void edge_attn_kernel(
    const __fp16* __restrict__ qf, const unsigned char* __restrict__ k8,
    const __fp16* __restrict__ v16, const float* __restrict__ adj_vals,
    const int* __restrict__ cols, const int* __restrict__ row_ptr,
    float* __restrict__ out, int n)
{
    int row = blockIdx.x * 4 + (threadIdx.x >> 6);
    if (row >= n) return;
    int lane    = threadIdx.x & 63;
    int quarter = lane >> 4;
    int l16     = lane & 15;

    int start = row_ptr[row];
    int end   = row_ptr[row + 1];

    float qv[8];
    {
        hf8 q8 = *(const hf8*)(qf + (size_t)row * DIM + l16 * 8);
#pragma unroll
        for (int j = 0; j < 8; ++j) qv[j] = (float)q8[j];
    }

    float s_sum = 0.0f;
    float acc[8];
#pragma unroll
    for (int j = 0; j < 8; ++j) acc[j] = 0.0f;

    const float scale = 0.08838834764831845f;   // 1/sqrt(128)

    for (int g = start; g < end; g += 8) {
        int eA = g + quarter;
        int eB = g + 4 + quarter;
        bool vA = eA < end;
        bool vB = eB < end;
        int last = end - 1;
        int iA = vA ? eA : last;
        int iB = vB ? eB : last;
        int   cA = cols[iA];
        int   cB = cols[iB];
        float aA = adj_vals[iA] * scale;
        float aB = adj_vals[iB] * scale;

        uint2 rA = *(const uint2*)(k8 + (size_t)cA * DIM + l16 * 8);
        uint2 rB = *(const uint2*)(k8 + (size_t)cB * DIM + l16 * 8);
        hf8 vA8 = *(const hf8*)(v16 + (size_t)cA * DIM + l16 * 8);
        hf8 vB8 = *(const hf8*)(v16 + (size_t)cB * DIM + l16 * 8);

        float dA = 0.0f, dB = 0.0f;
        dot_fp8x4(dA, rA.x, qv);
        dot_fp8x4(dA, rA.y, qv + 4);
        dot_fp8x4(dB, rB.x, qv);
        dot_fp8x4(dB, rB.y, qv + 4);
        dA += __shfl_xor(dA, 1); dB += __shfl_xor(dB, 1);
        dA += __shfl_xor(dA, 2); dB += __shfl_xor(dB, 2);
        dA += __shfl_xor(dA, 4); dB += __shfl_xor(dB, 4);
        dA += __shfl_xor(dA, 8); dB += __shfl_xor(dB, 8);

        float pA_ = vA ? __expf(dA * aA) : 0.0f;
        float pB_ = vB ? __expf(dB * aB) : 0.0f;
        s_sum += pA_ + pB_;
#pragma unroll
        for (int j = 0; j < 8; ++j)
            acc[j] += pA_ * (float)vA8[j] + pB_ * (float)vB8[j];
    }

    // merge the 4 quarter groups
    s_sum += __shfl_xor(s_sum, 16);
    s_sum += __shfl_xor(s_sum, 32);
#pragma unroll
    for (int j = 0; j < 8; ++j) {
        acc[j] += __shfl_xor(acc[j], 16);
        acc[j] += __shfl_xor(acc[j], 32);
    }
    float inv = (s_sum > 0.0f) ? 1.0f / s_sum : 0.0f;   // empty row -> zeros

    if (quarter == 0) {
        float4* dst = (float4*)(out + (size_t)row * DIM + l16 * 8);
        dst[0] = make_float4(acc[0] * inv, acc[1] * inv, acc[2] * inv, acc[3] * inv);
        dst[1] = make_float4(acc[4] * inv, acc[5] * inv, acc[6] * inv, acc[7] * inv);
    }
}

// ---------------------------------------------------------------------------
extern "C" void kernel_launch(void* const* d_in, const int* in_sizes, int n_in,
                              void* d_out, int out_size, void* d_ws, size_t ws_size,
                              hipStream_t stream)
{
    const float* query    = (const float*)d_in[0];
    const float* memory   = (const float*)d_in[1];
    const float* adj_vals = (const float*)d_in[2];
    const float* Wq       = (const float*)d_in[3];
    const float* bq       = (const float*)d_in[4];
    const float* Wk       = (const float*)d_in[5];
    const float* bk       = (const float*)d_in[6];
    const float* Wv       = (const float*)d_in[7];
    const float* bv       = (const float*)d_in[8];
    const int*   rows     = (const int*)d_in[9];
    const int*   cols     = (const int*)d_in[10];
    float* out = (float*)d_out;

    int n = in_sizes[0] / DIM;   // 50000
    int m = in_sizes[1] / DIM;   // 50000
    int e = in_sizes[9];         // 1600000

    // workspace layout (16B-aligned)
    char* ws = (char*)d_ws;
    size_t off = 0;
    _Float16* Wt = (_Float16*)(ws + off); off += (size_t)3 * DIM * DIM * 2;    // 96KB
    _Float16* qf = (_Float16*)(ws + off); off += (size_t)n * DIM * 2;          // 12.8MB
    _Float16* v16 = (_Float16*)(ws + off); off += (size_t)m * DIM * 2;         // 12.8MB
    unsigned char* k8 = (unsigned char*)(ws + off); off += (size_t)m * DIM;    // 6.4MB
    int* row_ptr = (int*)(ws + off);      off += (size_t)(n + 1) * 4;

    prep_w_kernel<<<dim3(64, 3), 256, 0, stream>>>(Wq, Wk, Wv, Wt);

    row_ptr_kernel<<<dim3((n + 1 + 255) / 256), 256, 0, stream>>>(rows, row_ptr, n, e);

    proj_gemm_kernel<<<dim3((n + 127) / 128, 3), 256, 0, stream>>>(
        query, memory, Wt, bq, bk, bv, qf, k8, v16, n, m);

    edge_attn_kernel<<<dim3((n + 3) / 4), 256, 0, stream>>>(
        (const __fp16*)qf, k8, (const __fp16*)v16, adj_vals, cols, row_ptr, out, n);
}